// Round 11
// baseline (36.936 us; speedup 1.0000x reference)
//
#include <hip/hip_runtime.h>
#include <hip/hip_bf16.h>

#define NB 4096      // batch
#define NC 100000    // classes
#define ND 256       // feature dim
#define MOM 0.01f

#define CHAIN_BLOCKS (NB / 4)        // 1024 blocks, 4 waves each = 4096 waves
#define COPY_BLOCKS  ((NC * ND / 4) / 2048)  // 3125 blocks * 2048 float4

typedef float f32x4 __attribute__((ext_vector_type(4)));

// Fused kernel (chain blocks first, then copy blocks).
//  Chain path: one wave per sample; chain-head waves compute the final row
//    for their class and write it to out.
//  Copy path: copy 32 aligned rows feat -> out with BRANCH-FREE stores:
//    every thread issues all 8 NT stores; stores for rows owned by chain
//    waves are redirected to a dummy sink in d_ws (address predication).
//    This removes all control flow between the 8 loads and 8 stores so the
//    full MLP=8 pipeline stays live (R9/R10 evidence: conditional stores
//    kept VGPR=24, i.e. loads were not all in flight).
__global__ __launch_bounds__(256) void mb_fused_kernel(
        const float* __restrict__ inputs,
        const int* __restrict__ targets,
        const float* __restrict__ feat_in,
        float* __restrict__ out,
        float* __restrict__ sink) {
    __shared__ int4 tg4[NB / 4];   // 16 KB, chain path
    __shared__ int flags[32];      // copy path
    int t = threadIdx.x;

    if (blockIdx.x < CHAIN_BLOCKS) {
        // ---- chain path ----
        #pragma unroll
        for (int k = 0; k < 4; ++k)
            tg4[t + k * 256] =
                reinterpret_cast<const int4*>(targets)[t + k * 256];
        __syncthreads();

        const int* tg = reinterpret_cast<const int*>(tg4);
        int wave = (blockIdx.x * 256 + t) >> 6;   // global sample id
        int lane = t & 63;
        int y = tg[wave];

        // Head check: does y appear at any index < wave? (256 targets/iter)
        for (int base = 0; base < wave; base += 256) {
            int4 v = tg4[(base >> 2) + lane];
            int j0 = base + lane * 4;
            bool m = (j0 < wave && v.x == y) | (j0 + 1 < wave && v.y == y)
                   | (j0 + 2 < wave && v.z == y) | (j0 + 3 < wave && v.w == y);
            if (__ballot(m)) return;  // not the chain head
        }

        // Initial row from ORIGINAL features_memory.
        float4 row = *reinterpret_cast<const float4*>(
            feat_in + (size_t)y * ND + lane * 4);

        // Walk samples j >= wave with targets[j] == y, in index order.
        for (int base = wave & ~255; base < NB; base += 256) {
            int4 v = tg4[(base >> 2) + lane];
            int j0 = base + lane * 4;
            unsigned lm = 0;
            lm |= (j0     >= wave && v.x == y) ? 1u : 0u;
            lm |= (j0 + 1 >= wave && v.y == y) ? 2u : 0u;
            lm |= (j0 + 2 >= wave && v.z == y) ? 4u : 0u;
            lm |= (j0 + 3 >= wave && v.w == y) ? 8u : 0u;
            unsigned long long wm = __ballot(lm != 0);
            while (wm) {
                int L = __ffsll((long long)wm) - 1;
                wm &= wm - 1ull;
                unsigned lmL = (unsigned)__shfl((int)lm, L);
                while (lmL) {
                    int k = __ffs((int)lmL) - 1;
                    lmL &= lmL - 1u;
                    int jj = base + L * 4 + k;
                    float4 x = *reinterpret_cast<const float4*>(
                        inputs + (size_t)jj * ND + lane * 4);
                    row.x = fmaf(MOM, row.x, (1.0f - MOM) * x.x);
                    row.y = fmaf(MOM, row.y, (1.0f - MOM) * x.y);
                    row.z = fmaf(MOM, row.z, (1.0f - MOM) * x.z);
                    row.w = fmaf(MOM, row.w, (1.0f - MOM) * x.w);
                    float ss = row.x * row.x + row.y * row.y
                             + row.z * row.z + row.w * row.w;
                    #pragma unroll
                    for (int off = 32; off > 0; off >>= 1)
                        ss += __shfl_xor(ss, off);
                    float inv = 1.0f / sqrtf(ss);
                    row.x *= inv; row.y *= inv; row.z *= inv; row.w *= inv;
                }
            }
        }

        *reinterpret_cast<float4*>(out + (size_t)y * ND + lane * 4) = row;
    } else {
        // ---- copy path ----
        int cb = blockIdx.x - CHAIN_BLOCKS;
        int r0 = cb * 32;  // first of the 32 rows this block covers

        // Issue ALL 8 data loads first (independent of the scan).
        const f32x4* src = reinterpret_cast<const f32x4*>(feat_in);
        f32x4* dst = reinterpret_cast<f32x4*>(out);
        f32x4* snk = reinterpret_cast<f32x4*>(sink);
        size_t base = (size_t)cb * 2048 + t;
        f32x4 v0 = src[base];
        f32x4 v1 = src[base + 256];
        f32x4 v2 = src[base + 512];
        f32x4 v3 = src[base + 768];
        f32x4 v4 = src[base + 1024];
        f32x4 v5 = src[base + 1280];
        f32x4 v6 = src[base + 1536];
        f32x4 v7 = src[base + 1792];

        if (t < 32) flags[t] = 0;
        __syncthreads();

        // Target scan overlaps the in-flight data loads.
        const int4* tgg = reinterpret_cast<const int4*>(targets);
        #pragma unroll
        for (int k = 0; k < 4; ++k) {
            int4 v = tgg[t + k * 256];
            if ((unsigned)(v.x - r0) < 32u) flags[v.x - r0] = 1;
            if ((unsigned)(v.y - r0) < 32u) flags[v.y - r0] = 1;
            if ((unsigned)(v.z - r0) < 32u) flags[v.z - r0] = 1;
            if ((unsigned)(v.w - r0) < 32u) flags[v.w - r0] = 1;
        }
        __syncthreads();

        // Branch-free stores: redirect flagged rows to the dummy sink.
        // Access k covers local row w + 4k (wave-uniform).
        int w = t >> 6;
        f32x4* d0 = flags[w     ] ? snk + t : dst + base;
        f32x4* d1 = flags[w +  4] ? snk + t : dst + base + 256;
        f32x4* d2 = flags[w +  8] ? snk + t : dst + base + 512;
        f32x4* d3 = flags[w + 12] ? snk + t : dst + base + 768;
        f32x4* d4 = flags[w + 16] ? snk + t : dst + base + 1024;
        f32x4* d5 = flags[w + 20] ? snk + t : dst + base + 1280;
        f32x4* d6 = flags[w + 24] ? snk + t : dst + base + 1536;
        f32x4* d7 = flags[w + 28] ? snk + t : dst + base + 1792;
        __builtin_nontemporal_store(v0, d0);
        __builtin_nontemporal_store(v1, d1);
        __builtin_nontemporal_store(v2, d2);
        __builtin_nontemporal_store(v3, d3);
        __builtin_nontemporal_store(v4, d4);
        __builtin_nontemporal_store(v5, d5);
        __builtin_nontemporal_store(v6, d6);
        __builtin_nontemporal_store(v7, d7);
    }
}

extern "C" void kernel_launch(void* const* d_in, const int* in_sizes, int n_in,
                              void* d_out, int out_size, void* d_ws, size_t ws_size,
                              hipStream_t stream) {
    const float* inputs  = (const float*)d_in[0];   // [NB, ND]
    const int*   targets = (const int*)d_in[1];     // [NB]
    const float* feat    = (const float*)d_in[2];   // [NC, ND]
    float* out = (float*)d_out;                     // [NC, ND]
    float* sink = (float*)d_ws;                     // >= 4 KB dummy window

    mb_fused_kernel<<<CHAIN_BLOCKS + COPY_BLOCKS, 256, 0, stream>>>(
        inputs, targets, feat, out, sink);
}

// Round 12
// 36.091 us; speedup vs baseline: 1.0234x; 1.0234x over previous
//
#include <hip/hip_runtime.h>
#include <hip/hip_bf16.h>

#define NB 4096      // batch
#define NC 100000    // classes
#define ND 256       // feature dim
#define MOM 0.01f

#define CHAIN_BLOCKS (NB / 4)        // 1024 blocks, 4 waves each = 4096 waves
#define COPY_BLOCKS  ((NC * ND / 4) / 2048)  // 3125 blocks * 2048 float4

typedef float f32x4 __attribute__((ext_vector_type(4)));

// Fused kernel (chain blocks first, then copy blocks). BEST CONFIG (R10):
//  - chain path: one wave per sample, LDS-staged targets, head waves only
//  - copy path: 32 rows/block, 8 hoisted+pinned loads (MLP=8), NT stores,
//    wave-uniform conditional stores skip chain-owned rows
//  - normal loads for feat (~50% L3 hit), NT stores for out
__global__ __launch_bounds__(256) void mb_fused_kernel(
        const float* __restrict__ inputs,
        const int* __restrict__ targets,
        const float* __restrict__ feat_in,
        float* __restrict__ out) {
    __shared__ int4 tg4[NB / 4];   // 16 KB, chain path
    __shared__ int flags[32];      // copy path
    int t = threadIdx.x;

    if (blockIdx.x < CHAIN_BLOCKS) {
        // ---- chain path ----
        #pragma unroll
        for (int k = 0; k < 4; ++k)
            tg4[t + k * 256] =
                reinterpret_cast<const int4*>(targets)[t + k * 256];
        __syncthreads();

        const int* tg = reinterpret_cast<const int*>(tg4);
        int wave = (blockIdx.x * 256 + t) >> 6;   // global sample id
        int lane = t & 63;
        int y = tg[wave];

        // Head check: does y appear at any index < wave? (256 targets/iter)
        for (int base = 0; base < wave; base += 256) {
            int4 v = tg4[(base >> 2) + lane];
            int j0 = base + lane * 4;
            bool m = (j0 < wave && v.x == y) | (j0 + 1 < wave && v.y == y)
                   | (j0 + 2 < wave && v.z == y) | (j0 + 3 < wave && v.w == y);
            if (__ballot(m)) return;  // not the chain head
        }

        // Initial row from ORIGINAL features_memory.
        float4 row = *reinterpret_cast<const float4*>(
            feat_in + (size_t)y * ND + lane * 4);

        // Walk samples j >= wave with targets[j] == y, in index order.
        for (int base = wave & ~255; base < NB; base += 256) {
            int4 v = tg4[(base >> 2) + lane];
            int j0 = base + lane * 4;
            unsigned lm = 0;
            lm |= (j0     >= wave && v.x == y) ? 1u : 0u;
            lm |= (j0 + 1 >= wave && v.y == y) ? 2u : 0u;
            lm |= (j0 + 2 >= wave && v.z == y) ? 4u : 0u;
            lm |= (j0 + 3 >= wave && v.w == y) ? 8u : 0u;
            unsigned long long wm = __ballot(lm != 0);
            while (wm) {
                int L = __ffsll((long long)wm) - 1;
                wm &= wm - 1ull;
                unsigned lmL = (unsigned)__shfl((int)lm, L);
                while (lmL) {
                    int k = __ffs((int)lmL) - 1;
                    lmL &= lmL - 1u;
                    int jj = base + L * 4 + k;
                    float4 x = *reinterpret_cast<const float4*>(
                        inputs + (size_t)jj * ND + lane * 4);
                    row.x = fmaf(MOM, row.x, (1.0f - MOM) * x.x);
                    row.y = fmaf(MOM, row.y, (1.0f - MOM) * x.y);
                    row.z = fmaf(MOM, row.z, (1.0f - MOM) * x.z);
                    row.w = fmaf(MOM, row.w, (1.0f - MOM) * x.w);
                    float ss = row.x * row.x + row.y * row.y
                             + row.z * row.z + row.w * row.w;
                    #pragma unroll
                    for (int off = 32; off > 0; off >>= 1)
                        ss += __shfl_xor(ss, off);
                    float inv = 1.0f / sqrtf(ss);
                    row.x *= inv; row.y *= inv; row.z *= inv; row.w *= inv;
                }
            }
        }

        *reinterpret_cast<float4*>(out + (size_t)y * ND + lane * 4) = row;
    } else {
        // ---- copy path ----
        int cb = blockIdx.x - CHAIN_BLOCKS;
        int r0 = cb * 32;  // first of the 32 rows this block covers

        // Issue ALL 8 data loads first (independent of the scan).
        const f32x4* src = reinterpret_cast<const f32x4*>(feat_in);
        f32x4* dst = reinterpret_cast<f32x4*>(out);
        size_t base = (size_t)cb * 2048 + t;
        f32x4 v0 = src[base];
        f32x4 v1 = src[base + 256];
        f32x4 v2 = src[base + 512];
        f32x4 v3 = src[base + 768];
        f32x4 v4 = src[base + 1024];
        f32x4 v5 = src[base + 1280];
        f32x4 v6 = src[base + 1536];
        f32x4 v7 = src[base + 1792];

        if (t < 32) flags[t] = 0;
        __syncthreads();

        // Target scan overlaps the in-flight data loads.
        const int4* tgg = reinterpret_cast<const int4*>(targets);
        #pragma unroll
        for (int k = 0; k < 4; ++k) {
            int4 v = tgg[t + k * 256];
            if ((unsigned)(v.x - r0) < 32u) flags[v.x - r0] = 1;
            if ((unsigned)(v.y - r0) < 32u) flags[v.y - r0] = 1;
            if ((unsigned)(v.z - r0) < 32u) flags[v.z - r0] = 1;
            if ((unsigned)(v.w - r0) < 32u) flags[v.w - r0] = 1;
        }
        __syncthreads();

        // Pin all 8 values live here: forces unconditional materialization,
        // preventing LLVM from sinking each load into its store branch.
        asm volatile("" : "+v"(v0), "+v"(v1), "+v"(v2), "+v"(v3),
                          "+v"(v4), "+v"(v5), "+v"(v6), "+v"(v7));

        int w = t >> 6;  // local row of access k is w + 4k (wave-uniform)
        if (!flags[w     ]) __builtin_nontemporal_store(v0, dst + base);
        if (!flags[w +  4]) __builtin_nontemporal_store(v1, dst + base + 256);
        if (!flags[w +  8]) __builtin_nontemporal_store(v2, dst + base + 512);
        if (!flags[w + 12]) __builtin_nontemporal_store(v3, dst + base + 768);
        if (!flags[w + 16]) __builtin_nontemporal_store(v4, dst + base + 1024);
        if (!flags[w + 20]) __builtin_nontemporal_store(v5, dst + base + 1280);
        if (!flags[w + 24]) __builtin_nontemporal_store(v6, dst + base + 1536);
        if (!flags[w + 28]) __builtin_nontemporal_store(v7, dst + base + 1792);
    }
}

extern "C" void kernel_launch(void* const* d_in, const int* in_sizes, int n_in,
                              void* d_out, int out_size, void* d_ws, size_t ws_size,
                              hipStream_t stream) {
    const float* inputs  = (const float*)d_in[0];   // [NB, ND]
    const int*   targets = (const int*)d_in[1];     // [NB]
    const float* feat    = (const float*)d_in[2];   // [NC, ND]
    float* out = (float*)d_out;                     // [NC, ND]

    mb_fused_kernel<<<CHAIN_BLOCKS + COPY_BLOCKS, 256, 0, stream>>>(
        inputs, targets, feat, out);
}